// Round 15
// baseline (603.046 us; speedup 1.0000x reference)
//
#include <hip/hip_runtime.h>
#include <stdint.h>

// ---------------------------------------------------------------------------
// GCN with chunk-major gather tables (per-XCD L2-resident):
//   Xc[8][M][32] bf16 — chunk c pinned to XCD c via blockIdx&7 (r5: FETCH
//   191->39MB proved the pinning). 8 lanes/edge x 8B, 8 edges per wave-load,
//   srcW={src_byte_off_in_chunk, dinv[src]} (no dependent dinv load).
//   agg1 = A_hat x   (gather_chunk, + mask1 bitmap in 1-of-8 chunk blocks)
//   h    = relu+drop(agg1 W1 + b1)   (MFMA GEMM, mask1 bit-test)
//   hw2  = h W2                      (MFMA GEMM, chunk-major C store)
//   out  = relu+drop(A_hat hw2 + b2) (gather_chunk + mask2 bit-test)
// ---------------------------------------------------------------------------

#define N_NODES 50000
#define N_EDGES 800000
#define M_PAD   50048   // 391 * 128
#define IN_C 256
#define HID_C 512
#define OUT_C 256
#define CH ((size_t)M_PAD * 32)   // ushorts per chunk (3.2 MB)

typedef __attribute__((ext_vector_type(8))) short bf16x8;
typedef __attribute__((ext_vector_type(4))) float f32x4;

struct U2 { unsigned a, b; };

__host__ __device__ constexpr unsigned rotl32(unsigned x, int d) {
  return (x << d) | (x >> (32 - d));
}

#define TF_ROUND(r) { x0 += x1; x1 = rotl32(x1, (r)); x1 ^= x0; }

__host__ __device__ constexpr U2 threefry2x32(unsigned k0, unsigned k1,
                                              unsigned x0, unsigned x1) {
  unsigned ks2 = k0 ^ k1 ^ 0x1BD11BDAu;
  x0 += k0; x1 += k1;
  TF_ROUND(13) TF_ROUND(15) TF_ROUND(26) TF_ROUND(6)  x0 += k1;  x1 += ks2 + 1u;
  TF_ROUND(17) TF_ROUND(29) TF_ROUND(16) TF_ROUND(24) x0 += ks2; x1 += k0 + 2u;
  TF_ROUND(13) TF_ROUND(15) TF_ROUND(26) TF_ROUND(6)  x0 += k0;  x1 += k1 + 3u;
  TF_ROUND(17) TF_ROUND(29) TF_ROUND(16) TF_ROUND(24) x0 += k1;  x1 += ks2 + 4u;
  TF_ROUND(13) TF_ROUND(15) TF_ROUND(26) TF_ROUND(6)  x0 += ks2; x1 += k0 + 5u;
  return U2{x0, x1};
}

__device__ __forceinline__ ushort f2b(float f) {  // RTNE
  unsigned u = __builtin_bit_cast(unsigned, f);
  unsigned r = (u + 0x7fffu + ((u >> 16) & 1u)) >> 16;
  return (ushort)r;
}
__device__ __forceinline__ float b2f_hi(unsigned u) {
  return __builtin_bit_cast(float, u & 0xffff0000u);
}
__device__ __forceinline__ float b2f_lo(unsigned u) {
  return __builtin_bit_cast(float, u << 16);
}

__device__ __forceinline__ void acc4(float (&a)[4], uint2 u, float wgt) {
  a[0] += b2f_lo(u.x) * wgt; a[1] += b2f_hi(u.x) * wgt;
  a[2] += b2f_lo(u.y) * wgt; a[3] += b2f_hi(u.y) * wgt;
}

__device__ __forceinline__ void gload16(const void* g, void* l) {
  __builtin_amdgcn_global_load_lds(
      (const __attribute__((address_space(1))) void*)g,
      (__attribute__((address_space(3))) void*)l, 16, 0, 0);
}

// ---------------------------------------------------------------------------
// degree / scan(+dinv) / merged chunk-scan+add / CSR build
// CSR entry = {src*64 (byte offset within a chunk), dinv[src]}
// ---------------------------------------------------------------------------
__global__ void deg_kernel(const int* __restrict__ col, int* __restrict__ cnt, int E) {
  int e = blockIdx.x * 256 + threadIdx.x;
  if (e < E) atomicAdd(&cnt[col[e]], 1);
}

__global__ __launch_bounds__(1024) void scan_local(const int* __restrict__ cnt,
                                                   int* __restrict__ indptr,
                                                   int* __restrict__ chunkSums,
                                                   float* __restrict__ dinv, int n) {
  __shared__ int s[1024];
  int gid = blockIdx.x * 1024 + threadIdx.x;
  int v = (gid < n) ? cnt[gid] : 0;
  if (gid < n) dinv[gid] = rsqrtf((float)v + 1.0f);
  s[threadIdx.x] = v;
  __syncthreads();
#pragma unroll
  for (int off = 1; off < 1024; off <<= 1) {
    int t = (threadIdx.x >= off) ? s[threadIdx.x - off] : 0;
    __syncthreads();
    s[threadIdx.x] += t;
    __syncthreads();
  }
  if (gid < n) indptr[gid] = s[threadIdx.x] - v;
  if (threadIdx.x == 1023) chunkSums[blockIdx.x] = s[1023];
}

__global__ void scan_add(int* __restrict__ indptr, const int* __restrict__ chunkSums,
                         int n, int nChunks, int total) {
  __shared__ int sc[64];
  int gid = blockIdx.x * 256 + threadIdx.x;
  if (threadIdx.x < 64) {
    int lane = threadIdx.x;
    int v = (lane < nChunks) ? chunkSums[lane] : 0;
    int incl = v;
#pragma unroll
    for (int off = 1; off < 64; off <<= 1) {
      int t = __shfl_up(incl, off);
      if (lane >= off) incl += t;
    }
    sc[lane] = incl - v;  // exclusive prefix
  }
  __syncthreads();
  if (gid < n) indptr[gid] += sc[gid >> 10];
  if (gid == 0) indptr[n] = total;
}

__global__ void build_csr(const int* __restrict__ row, const int* __restrict__ col,
                          const int* __restrict__ indptr, int* __restrict__ cursor,
                          const float* __restrict__ dinv,
                          int2* __restrict__ srcW, int E) {
  int e = blockIdx.x * 256 + threadIdx.x;
  if (e < E) {
    int r = row[e];
    int c = col[e];
    int p = indptr[c] + atomicAdd(&cursor[c], 1);
    srcW[p] = make_int2(r << 6, __builtin_bit_cast(int, dinv[r]));  // 64B/row-chunk
  }
}

// ---------------------------------------------------------------------------
// prep: x -> chunk-major bf16 Xc, mask2 bitmap gen, W transposes, pad zero.
// ---------------------------------------------------------------------------
__global__ void prep(const float* __restrict__ x, ushort* __restrict__ x16c, int n4,
                     unsigned char* __restrict__ mask2,
                     unsigned k20, unsigned k21, int nMaskBytes,
                     const float* __restrict__ W1, const float* __restrict__ W2,
                     ushort* __restrict__ W1T, ushort* __restrict__ W2T,
                     ushort* __restrict__ padDst) {
  int i = blockIdx.x * 256 + threadIdx.x;
  if (i < n4) {
    int n = i >> 6;
    int f = (i & 63) * 4;
    int c = f >> 5, fi = f & 31;
    float4 v = *(const float4*)(x + (size_t)i * 4);
    ushort4 o = make_ushort4(f2b(v.x), f2b(v.y), f2b(v.z), f2b(v.w));
    *(ushort4*)(x16c + (size_t)c * CH + (size_t)n * 32 + fi) = o;
  }
  if (i < nMaskBytes) {
    unsigned eb = (unsigned)i * 8u;
    unsigned byte = 0;
#pragma unroll
    for (int j = 0; j < 8; ++j) {
      U2 r = threefry2x32(k20, k21, 0u, eb + (unsigned)j);
      byte |= (((r.a ^ r.b) >> 31) & 1u) << j;
    }
    mask2[i] = (unsigned char)byte;
  }
  if (i < IN_C * HID_C) {        // W1T[n][k] = bf16(W1[k][n])
    int k = i & (IN_C - 1);
    int n = i >> 8;
    W1T[i] = f2b(W1[(size_t)k * HID_C + n]);
  } else if (i < IN_C * HID_C + HID_C * OUT_C) {
    int j = i - IN_C * HID_C;    // W2T[n][k] = bf16(W2[k][n])
    int k = j & (HID_C - 1);
    int n = j >> 9;
    W2T[j] = f2b(W2[(size_t)k * OUT_C + n]);
  }
  if (i < (M_PAD - N_NODES) * IN_C / 8) {  // zero pad rows of aggB
    uint4 z = {0u, 0u, 0u, 0u};
    *(uint4*)(padDst + (size_t)i * 8) = z;
  }
}

// ---------------------------------------------------------------------------
// chunked gather: grid = 8 * ceil(N/4); c = bid&7 (XCD pin), 4 waves/block,
// one node per wave. lane: slot=lane>>3 (8 edges in parallel), fp=lane&7
// (4 features of chunk c). 2-batch unroll = 16 edges in flight.
// EPI=false: bf16 node-major out + mask1 bitmap when (g&7)==c.
// EPI=true : bias+relu+mask2-bit dropout, fp32 out.
// ---------------------------------------------------------------------------
template <bool EPI>
__global__ __launch_bounds__(256) void gather_chunk(const ushort* __restrict__ Xc,
                                                    const int* __restrict__ indptr,
                                                    const int2* __restrict__ srcW,
                                                    const float* __restrict__ dinv,
                                                    const float* __restrict__ bias,
                                                    void* __restrict__ outp,
                                                    unsigned char* __restrict__ mask1Gen,
                                                    const unsigned char* __restrict__ maskUse,
                                                    unsigned k10, unsigned k11, int N) {
  const int bid = blockIdx.x;
  const int c = bid & 7;
  const int g = bid >> 3;
  const int wv = threadIdx.x >> 6;
  const int lane = threadIdx.x & 63;
  const int n = g * 4 + wv;
  if (n >= N) return;
  const int slot = lane >> 3;
  const int fp = lane & 7;
  const int beg = __builtin_amdgcn_readfirstlane(indptr[n]);
  const int end = __builtin_amdgcn_readfirstlane(indptr[n + 1]);
  const float dc = dinv[n];
  const char* Xb = (const char*)(Xc + (size_t)c * CH) + fp * 8;

  float a[4] = {};
  if (slot == 0) {  // self-loop
    uint2 u = *(const uint2*)(Xb + ((size_t)n << 6));
    acc4(a, u, dc);
  }
  int e = beg;
  for (; e + 16 <= end; e += 16) {
    int2 qa = srcW[e + slot];
    int2 qb = srcW[e + 8 + slot];
    uint2 ua = *(const uint2*)(Xb + (unsigned)qa.x);
    uint2 ub = *(const uint2*)(Xb + (unsigned)qb.x);
    acc4(a, ua, __builtin_bit_cast(float, qa.y));
    acc4(a, ub, __builtin_bit_cast(float, qb.y));
  }
  if (e + 8 <= end) {
    int2 q = srcW[e + slot];
    uint2 u = *(const uint2*)(Xb + (unsigned)q.x);
    acc4(a, u, __builtin_bit_cast(float, q.y));
    e += 8;
  }
  if (e + slot < end) {
    int2 q = srcW[e + slot];
    uint2 u = *(const uint2*)(Xb + (unsigned)q.x);
    acc4(a, u, __builtin_bit_cast(float, q.y));
  }
  // reduce across the 8 edge-slots
#pragma unroll
  for (int j = 0; j < 4; ++j) {
    a[j] += __shfl_xor(a[j], 8);
    a[j] += __shfl_xor(a[j], 16);
    a[j] += __shfl_xor(a[j], 32);
    a[j] *= dc;
  }

  if (EPI) {
    if (slot == 0) {
      int f = c * 32 + fp * 4;
      float4 bv = *(const float4*)(bias + f);
      unsigned mk = maskUse[(size_t)n * 32 + c * 4 + (fp >> 1)];
      int sh = (fp & 1) * 4;
      float v0 = fmaxf(a[0] + bv.x, 0.f);
      float v1 = fmaxf(a[1] + bv.y, 0.f);
      float v2 = fmaxf(a[2] + bv.z, 0.f);
      float v3 = fmaxf(a[3] + bv.w, 0.f);
      v0 = ((mk >> (sh + 0)) & 1u) ? 0.f : v0 * 2.0f;
      v1 = ((mk >> (sh + 1)) & 1u) ? 0.f : v1 * 2.0f;
      v2 = ((mk >> (sh + 2)) & 1u) ? 0.f : v2 * 2.0f;
      v3 = ((mk >> (sh + 3)) & 1u) ? 0.f : v3 * 2.0f;
      *(float4*)((float*)outp + (size_t)n * 256 + f) = make_float4(v0, v1, v2, v3);
    }
  } else {
    if (slot == 0) {
      uint2 o;
      o.x = (unsigned)f2b(a[0]) | ((unsigned)f2b(a[1]) << 16);
      o.y = (unsigned)f2b(a[2]) | ((unsigned)f2b(a[3]) << 16);
      *(uint2*)((ushort*)outp + (size_t)n * 256 + c * 32 + fp * 4) = o;
    }
    // layer-1 mask: exactly one chunk-block per node-group generates it
    if ((g & 7) == c) {
      unsigned gl = (unsigned)n * 64u + (unsigned)lane;
      unsigned eb = gl * 8u;
      unsigned byte = 0;
#pragma unroll
      for (int j = 0; j < 8; ++j) {
        U2 r = threefry2x32(k10, k11, 0u, eb + (unsigned)j);
        byte |= (((r.a ^ r.b) >> 31) & 1u) << j;
      }
      mask1Gen[gl] = (unsigned char)byte;
    }
  }
}

// ---------------------------------------------------------------------------
// bf16 MFMA GEMM: C[M,N] = A[M,K] @ BT[N,K]^T.  128x128 tile, BK=64, 4 waves,
// single-buffer 32KB staging, XOR-swizzled, swapped-operand mfma (lane holds
// 4 contiguous cols -> direct 8B C stores). 1-D grid, bijective XCD swizzle.
// EPI: bias+relu+mask1-bit dropout. CHUNKOUT: store C chunk-major [8][M][32].
// ---------------------------------------------------------------------------
template <bool EPI, int NSTRIP, bool CHUNKOUT>
__global__ __launch_bounds__(256) void gemm_bf16(const ushort* __restrict__ A,
                                                 const ushort* __restrict__ BT,
                                                 ushort* __restrict__ C,
                                                 int M, int K, int N,
                                                 const float* __restrict__ bias,
                                                 const unsigned char* __restrict__ mask1) {
  __shared__ __align__(16) ushort lds[16384];  // A 16KB | B 16KB
  const int nwg = gridDim.x;
  const int orig = blockIdx.x;
  const int q = nwg >> 3, r = nwg & 7;
  const int xcd = orig & 7, loc = orig >> 3;
  const int wg = (xcd < r) ? (xcd * (q + 1) + loc)
                           : (r * (q + 1) + (xcd - r) * q + loc);
  const int bm = (wg / NSTRIP) * 128;
  const int bn = (wg % NSTRIP) * 128;

  const int tid = threadIdx.x;
  const int lane = tid & 63;
  const int wv = tid >> 6;
  const int wr = wv >> 1, wc = wv & 1;

  f32x4 acc[4][4] = {};
  const int xorv = (lane & 7) << 4;

  const int nt = K >> 6;
  for (int t = 0; t < nt; ++t) {
    const int k0 = t << 6;
#pragma unroll
    for (int l = 0; l < 4; ++l) {
      int cid = l * 256 + tid;
      int row = cid >> 3;
      int kcol = ((cid & 7) ^ (row & 7)) * 8;
      gload16(A + (size_t)(bm + row) * K + k0 + kcol, (void*)(lds + cid * 8));
      gload16(BT + (size_t)(bn + row) * K + k0 + kcol, (void*)(lds + 8192 + cid * 8));
    }
    __syncthreads();
    const char* Ab = (const char*)lds;
    const char* Bb = (const char*)(lds + 8192);
#pragma unroll
    for (int ks = 0; ks < 2; ++ks) {
      bf16x8 af[4], bf[4];
      const int kb = (ks * 64 + (lane >> 4) * 16) ^ xorv;
#pragma unroll
      for (int i = 0; i < 4; ++i) {
        int arow = wr * 64 + i * 16 + (lane & 15);
        af[i] = *(const bf16x8*)(Ab + arow * 128 + kb);
        int brow = wc * 64 + i * 16 + (lane & 15);
        bf[i] = *(const bf16x8*)(Bb + brow * 128 + kb);
      }
#pragma unroll
      for (int m = 0; m < 4; ++m)
#pragma unroll
        for (int n = 0; n < 4; ++n)
          acc[m][n] = __builtin_amdgcn_mfma_f32_16x16x32_bf16(bf[n], af[m], acc[m][n], 0, 0, 0);
    }
    __syncthreads();
  }

  const int growb = bm + wr * 64 + (lane & 15);
  const int gcolb = bn + wc * 64 + ((lane >> 4) << 2);
  float4 bias_v[4];
  if (EPI) {
#pragma unroll
    for (int n = 0; n < 4; ++n) bias_v[n] = *(const float4*)(bias + gcolb + n * 16);
  }
#pragma unroll
  for (int m = 0; m < 4; ++m) {
    int grow = growb + m * 16;
    unsigned long long mrow = 0;
    if (EPI)
      mrow = *(const unsigned long long*)(mask1 + (((size_t)grow * N + bn + wc * 64) >> 3));
#pragma unroll
    for (int n = 0; n < 4; ++n) {
      int gcol = gcolb + n * 16;
      float v[4];
#pragma unroll
      for (int r2 = 0; r2 < 4; ++r2) {
        float x = acc[m][n][r2];
        if (EPI) {
          x = fmaxf(x + ((const float*)&bias_v[n])[r2], 0.f);
          int bit = (gcol - (bn + wc * 64)) + r2;
          x = ((mrow >> bit) & 1ull) ? 0.f : x * 2.0f;
        }
        v[r2] = x;
      }
      uint2 o;
      o.x = (unsigned)f2b(v[0]) | ((unsigned)f2b(v[1]) << 16);
      o.y = (unsigned)f2b(v[2]) | ((unsigned)f2b(v[3]) << 16);
      if (CHUNKOUT) {
        int cch = gcol >> 5, fi = gcol & 31;
        *(uint2*)(C + (size_t)cch * CH + (size_t)grow * 32 + fi) = o;
      } else {
        *(uint2*)(C + (size_t)grow * N + gcol) = o;
      }
    }
  }
}

// ---------------------------------------------------------------------------
extern "C" void kernel_launch(void* const* d_in, const int* in_sizes, int n_in,
                              void* d_out, int out_size, void* d_ws, size_t ws_size,
                              hipStream_t stream) {
  const float* x  = (const float*)d_in[0];
  const int*   ei = (const int*)d_in[1];
  const float* W1 = (const float*)d_in[2];
  const float* b1 = (const float*)d_in[3];
  const float* W2 = (const float*)d_in[4];
  const float* b2 = (const float*)d_in[5];
  float* out = (float*)d_out;
  (void)in_sizes; (void)n_in; (void)out_size; (void)ws_size;

  const int* row = ei;
  const int* col = ei + N_EDGES;

  // workspace layout (bytes)
  char* ws = (char*)d_ws;
  float*  dinv      = (float*) (ws);                           // 200 KB
  int*    cnt       = (int*)   (ws + (1u << 18));              // 200 KB
  int*    cursor    = (int*)   (ws + (2u << 18));              // 200 KB (adjacent)
  int*    indptr    = (int*)   (ws + (3u << 18));              // 200 KB + 4
  int*    chunkSums = (int*)   (ws + (1u << 20));              // tiny
  int2*   srcW      = (int2*)  (ws + 2u * (1u << 20));         // 6.4 MB
  ushort* W1T       = (ushort*)(ws + 9u * (1u << 20));         // 256 KB [512][256]
  ushort* W2T       = (ushort*)(ws + 9u * (1u << 20) + (1u << 19)); // 256 KB
  unsigned char* mask1 = (unsigned char*)(ws + 10u * (1u << 20)); // 3.21 MB
  unsigned char* mask2 = (unsigned char*)(ws + 14u * (1u << 20)); // 1.61 MB
  ushort* x16c      = (ushort*)(ws + 18u * (1u << 20));        // 25.6 MB [8][M_PAD][32]
  ushort* aggB      = (ushort*)(ws + 44u * (1u << 20));        // 25.6 MB [M_PAD][256]
  ushort* h         = (ushort*)(ws + 70u * (1u << 20));        // 51.2 MB [M_PAD][512]
  ushort* hw2c      = (ushort*)(ws + 122u* (1u << 20));        // 25.6 MB [8][M_PAD][32]

  constexpr U2 K1 = threefry2x32(0u, 42u, 0u, 0u);
  constexpr U2 K2 = threefry2x32(0u, 42u, 0u, 1u);

  // ---- CSR build ----
  (void)hipMemsetAsync(cnt, 0, 2u * (1u << 18), stream);  // cnt + cursor
  deg_kernel<<<(N_EDGES + 255) / 256, 256, 0, stream>>>(col, cnt, N_EDGES);
  const int nChunks = (N_NODES + 1023) / 1024;
  scan_local<<<nChunks, 1024, 0, stream>>>(cnt, indptr, chunkSums, dinv, N_NODES);
  scan_add<<<(N_NODES + 255) / 256, 256, 0, stream>>>(indptr, chunkSums, N_NODES, nChunks, N_EDGES);
  build_csr<<<(N_EDGES + 255) / 256, 256, 0, stream>>>(row, col, indptr, cursor, dinv, srcW, N_EDGES);

  // ---- prep: cvt (chunk-major) + mask2 + W transposes + aggB pad zero ----
  prep<<<(N_NODES * IN_C / 4 + 255) / 256, 256, 0, stream>>>(
      x, x16c, N_NODES * IN_C / 4, mask2, K2.a, K2.b, N_NODES * 32,
      W1, W2, W1T, W2T, aggB + (size_t)N_NODES * IN_C);

  const int gatherGrid = 8 * ((N_NODES + 3) / 4);

  // ---- layer 1 ----
  gather_chunk<false><<<gatherGrid, 256, 0, stream>>>(
      x16c, indptr, srcW, dinv, nullptr, aggB, mask1, nullptr, K1.a, K1.b, N_NODES);
  gemm_bf16<true, HID_C / 128, false><<<(M_PAD / 128) * (HID_C / 128), 256, 0, stream>>>(
      aggB, W1T, h, M_PAD, IN_C, HID_C, b1, mask1);

  // ---- layer 2 ----
  gemm_bf16<false, OUT_C / 128, true><<<(M_PAD / 128) * (OUT_C / 128), 256, 0, stream>>>(
      h, W2T, hw2c, M_PAD, HID_C, OUT_C, nullptr, nullptr);
  gather_chunk<true><<<gatherGrid, 256, 0, stream>>>(
      hw2c, indptr, srcW, dinv, b2, out, nullptr, mask2, 0u, 0u, N_NODES);
}

// Round 16
// 395.439 us; speedup vs baseline: 1.5250x; 1.5250x over previous
//
#include <hip/hip_runtime.h>
#include <stdint.h>

// ---------------------------------------------------------------------------
// GCN: agg1 = A_hat x (LDS-staged gather + mask1 bitmap)
//      h    = relu+drop(agg1 W1 + b1)   (MFMA GEMM, mask1 bit-test)
//      hw2  = h W2                      (MFMA GEMM, plain)
//      out  = relu+drop(A_hat hw2 + b2) (LDS-staged gather + mask2 bit-test)
// Gather stages 16 edge-rows/wave (8KB) via async global_load_lds (no data
// VGPRs -> allocator can't serialize the MLP; vmcnt tracks 8 in-flight 1KB
// DMAs). mask2 generated in prep. CSR = {src_byte_off, dinv[src]}.
// ---------------------------------------------------------------------------

#define N_NODES 50000
#define N_EDGES 800000
#define M_PAD   50048   // 391 * 128
#define IN_C 256
#define HID_C 512
#define OUT_C 256

typedef __attribute__((ext_vector_type(8))) short bf16x8;
typedef __attribute__((ext_vector_type(4))) float f32x4;

struct U2 { unsigned a, b; };

__host__ __device__ constexpr unsigned rotl32(unsigned x, int d) {
  return (x << d) | (x >> (32 - d));
}

#define TF_ROUND(r) { x0 += x1; x1 = rotl32(x1, (r)); x1 ^= x0; }

__host__ __device__ constexpr U2 threefry2x32(unsigned k0, unsigned k1,
                                              unsigned x0, unsigned x1) {
  unsigned ks2 = k0 ^ k1 ^ 0x1BD11BDAu;
  x0 += k0; x1 += k1;
  TF_ROUND(13) TF_ROUND(15) TF_ROUND(26) TF_ROUND(6)  x0 += k1;  x1 += ks2 + 1u;
  TF_ROUND(17) TF_ROUND(29) TF_ROUND(16) TF_ROUND(24) x0 += ks2; x1 += k0 + 2u;
  TF_ROUND(13) TF_ROUND(15) TF_ROUND(26) TF_ROUND(6)  x0 += k0;  x1 += k1 + 3u;
  TF_ROUND(17) TF_ROUND(29) TF_ROUND(16) TF_ROUND(24) x0 += k1;  x1 += ks2 + 4u;
  TF_ROUND(13) TF_ROUND(15) TF_ROUND(26) TF_ROUND(6)  x0 += ks2; x1 += k0 + 5u;
  return U2{x0, x1};
}

__device__ __forceinline__ ushort f2b(float f) {  // RTNE
  unsigned u = __builtin_bit_cast(unsigned, f);
  unsigned r = (u + 0x7fffu + ((u >> 16) & 1u)) >> 16;
  return (ushort)r;
}
__device__ __forceinline__ float b2f_hi(unsigned u) {
  return __builtin_bit_cast(float, u & 0xffff0000u);
}
__device__ __forceinline__ float b2f_lo(unsigned u) {
  return __builtin_bit_cast(float, u << 16);
}

__device__ __forceinline__ void acc4u(float (&a)[4], uint2 u, float wgt) {
  a[0] += b2f_lo(u.x) * wgt; a[1] += b2f_hi(u.x) * wgt;
  a[2] += b2f_lo(u.y) * wgt; a[3] += b2f_hi(u.y) * wgt;
}

__device__ __forceinline__ void gload16(const void* g, void* l) {
  __builtin_amdgcn_global_load_lds(
      (const __attribute__((address_space(1))) void*)g,
      (__attribute__((address_space(3))) void*)l, 16, 0, 0);
}

// ---------------------------------------------------------------------------
// degree / scan(+dinv) / merged chunk-scan+add / CSR build
// CSR entry = {src*512 (byte offset), dinv[src]}
// ---------------------------------------------------------------------------
__global__ void deg_kernel(const int* __restrict__ col, int* __restrict__ cnt, int E) {
  int e = blockIdx.x * 256 + threadIdx.x;
  if (e < E) atomicAdd(&cnt[col[e]], 1);
}

__global__ __launch_bounds__(1024) void scan_local(const int* __restrict__ cnt,
                                                   int* __restrict__ indptr,
                                                   int* __restrict__ chunkSums,
                                                   float* __restrict__ dinv, int n) {
  __shared__ int s[1024];
  int gid = blockIdx.x * 1024 + threadIdx.x;
  int v = (gid < n) ? cnt[gid] : 0;
  if (gid < n) dinv[gid] = rsqrtf((float)v + 1.0f);
  s[threadIdx.x] = v;
  __syncthreads();
#pragma unroll
  for (int off = 1; off < 1024; off <<= 1) {
    int t = (threadIdx.x >= off) ? s[threadIdx.x - off] : 0;
    __syncthreads();
    s[threadIdx.x] += t;
    __syncthreads();
  }
  if (gid < n) indptr[gid] = s[threadIdx.x] - v;
  if (threadIdx.x == 1023) chunkSums[blockIdx.x] = s[1023];
}

__global__ void scan_add(int* __restrict__ indptr, const int* __restrict__ chunkSums,
                         int n, int nChunks, int total) {
  __shared__ int sc[64];
  int gid = blockIdx.x * 256 + threadIdx.x;
  if (threadIdx.x < 64) {
    int lane = threadIdx.x;
    int v = (lane < nChunks) ? chunkSums[lane] : 0;
    int incl = v;
#pragma unroll
    for (int off = 1; off < 64; off <<= 1) {
      int t = __shfl_up(incl, off);
      if (lane >= off) incl += t;
    }
    sc[lane] = incl - v;  // exclusive prefix
  }
  __syncthreads();
  if (gid < n) indptr[gid] += sc[gid >> 10];
  if (gid == 0) indptr[n] = total;
}

__global__ void build_csr(const int* __restrict__ row, const int* __restrict__ col,
                          const int* __restrict__ indptr, int* __restrict__ cursor,
                          const float* __restrict__ dinv,
                          int2* __restrict__ srcW, int E) {
  int e = blockIdx.x * 256 + threadIdx.x;
  if (e < E) {
    int r = row[e];
    int c = col[e];
    int p = indptr[c] + atomicAdd(&cursor[c], 1);
    srcW[p] = make_int2(r << 9, __builtin_bit_cast(int, dinv[r]));  // byte offset
  }
}

// ---------------------------------------------------------------------------
// prep: x->bf16 cvt, mask2 bitmap gen, W1T/W2T transpose-cvt, aggB pad zero.
// ---------------------------------------------------------------------------
__global__ void prep(const float* __restrict__ x, ushort* __restrict__ x16, int n4,
                     unsigned char* __restrict__ mask2,
                     unsigned k20, unsigned k21, int nMaskBytes,
                     const float* __restrict__ W1, const float* __restrict__ W2,
                     ushort* __restrict__ W1T, ushort* __restrict__ W2T,
                     ushort* __restrict__ padDst) {
  int i = blockIdx.x * 256 + threadIdx.x;
  if (i < n4) {
    float4 v = *(const float4*)(x + (size_t)i * 4);
    ushort4 o = make_ushort4(f2b(v.x), f2b(v.y), f2b(v.z), f2b(v.w));
    *(ushort4*)(x16 + (size_t)i * 4) = o;
  }
  if (i < nMaskBytes) {
    unsigned eb = (unsigned)i * 8u;
    unsigned byte = 0;
#pragma unroll
    for (int j = 0; j < 8; ++j) {
      U2 r = threefry2x32(k20, k21, 0u, eb + (unsigned)j);
      byte |= (((r.a ^ r.b) >> 31) & 1u) << j;
    }
    mask2[i] = (unsigned char)byte;
  }
  if (i < IN_C * HID_C) {        // W1T[n][k] = bf16(W1[k][n])
    int k = i & (IN_C - 1);
    int n = i >> 8;
    W1T[i] = f2b(W1[(size_t)k * HID_C + n]);
  } else if (i < IN_C * HID_C + HID_C * OUT_C) {
    int j = i - IN_C * HID_C;    // W2T[n][k] = bf16(W2[k][n])
    int k = j & (HID_C - 1);
    int n = j >> 9;
    W2T[j] = f2b(W2[(size_t)k * OUT_C + n]);
  }
  if (i < (M_PAD - N_NODES) * IN_C / 8) {  // zero pad rows of aggB
    uint4 z = {0u, 0u, 0u, 0u};
    *(uint4*)(padDst + (size_t)i * 8) = z;
  }
}

// ---------------------------------------------------------------------------
// LDS-staged gather: one wave per node. Per batch, stage up to 16 edge-rows
// (8KB) into this wave's private LDS slab via 8 global_load_lds (lanes 0-31
// -> edge 2j, lanes 32-63 -> edge 2j+1; per-lane GLOBAL addr, uniform LDS
// base + lane*16). Then vmcnt(0) + 16 conflict-free ds_read_b64 + FMA.
// EPI=false: bf16 out + mask1 bitmap. EPI=true: bias+relu+mask2 drop, fp32.
// ---------------------------------------------------------------------------
template <bool EPI>
__global__ __launch_bounds__(256) void gather_lds(const ushort* __restrict__ X,
                                                  const int* __restrict__ indptr,
                                                  const int2* __restrict__ srcW,
                                                  const float* __restrict__ dinv,
                                                  const float* __restrict__ bias,
                                                  void* __restrict__ outp,
                                                  unsigned char* __restrict__ mask1Gen,
                                                  const unsigned char* __restrict__ maskUse,
                                                  unsigned k10, unsigned k11, int N) {
  __shared__ __align__(16) ushort sbuf[4 * 16 * 256];  // 4 waves x 16 rows x 512B
  const int wv = threadIdx.x >> 6;
  const int lane = threadIdx.x & 63;
  const int wid = (blockIdx.x * 256 + threadIdx.x) >> 6;
  if (wid >= N) return;
  ushort* sw = sbuf + wv * 4096;  // this wave's slab

  const int beg = __builtin_amdgcn_readfirstlane(indptr[wid]);
  const int end = __builtin_amdgcn_readfirstlane(indptr[wid + 1]);
  const float dc = dinv[wid];
  const char* Xb = (const char*)X;

  float a[4] = {};
  {  // self-loop row (direct global load)
    uint2 u = *(const uint2*)(Xb + ((size_t)wid << 9) + lane * 8);
    acc4u(a, u, dc);
  }

  int e = beg;
  while (e < end) {
    int cnt = end - e;
    if (cnt > 16) cnt = 16;
    const int npair = (cnt + 1) >> 1;
#pragma unroll
    for (int j = 0; j < 8; ++j) {
      if (j < npair) {
        int i1 = 2 * j + (lane >> 5);
        if (i1 >= cnt) i1 = 2 * j;           // clamp (duplicate, never read)
        int2 q = srcW[e + i1];
        gload16(Xb + (unsigned)q.x + (lane & 31) * 16, (void*)(sw + j * 512));
      }
    }
    asm volatile("s_waitcnt vmcnt(0)" ::: "memory");
    __builtin_amdgcn_sched_barrier(0);
#pragma unroll
    for (int i = 0; i < 16; ++i) {
      if (i < cnt) {
        float w = __builtin_bit_cast(float, srcW[e + i].y);  // uniform, L1-hot
        uint2 u = *(const uint2*)(sw + i * 256 + lane * 4);
        acc4u(a, u, w);
      }
    }
    e += cnt;
  }
#pragma unroll
  for (int j = 0; j < 4; ++j) a[j] *= dc;

  const int f0 = lane * 4;
  if (EPI) {
    float4 bv = *(const float4*)(bias + f0);
    unsigned mk = maskUse[(size_t)wid * 32 + (lane >> 1)];
    int sh = (lane & 1) * 4;
    float v0 = fmaxf(a[0] + bv.x, 0.f);
    float v1 = fmaxf(a[1] + bv.y, 0.f);
    float v2 = fmaxf(a[2] + bv.z, 0.f);
    float v3 = fmaxf(a[3] + bv.w, 0.f);
    v0 = ((mk >> (sh + 0)) & 1u) ? 0.f : v0 * 2.0f;
    v1 = ((mk >> (sh + 1)) & 1u) ? 0.f : v1 * 2.0f;
    v2 = ((mk >> (sh + 2)) & 1u) ? 0.f : v2 * 2.0f;
    v3 = ((mk >> (sh + 3)) & 1u) ? 0.f : v3 * 2.0f;
    *(float4*)((float*)outp + (size_t)wid * 256 + f0) = make_float4(v0, v1, v2, v3);
  } else {
    uint2 o;
    o.x = (unsigned)f2b(a[0]) | ((unsigned)f2b(a[1]) << 16);
    o.y = (unsigned)f2b(a[2]) | ((unsigned)f2b(a[3]) << 16);
    *(uint2*)((ushort*)outp + (size_t)wid * 256 + f0) = o;
    // layer-1 mask: lane packs bits for h elements [gl*8, gl*8+8)
    unsigned gl = (unsigned)wid * 64u + (unsigned)lane;
    unsigned eb = gl * 8u;
    unsigned byte = 0;
#pragma unroll
    for (int j = 0; j < 8; ++j) {
      U2 r = threefry2x32(k10, k11, 0u, eb + (unsigned)j);
      byte |= (((r.a ^ r.b) >> 31) & 1u) << j;
    }
    mask1Gen[gl] = (unsigned char)byte;
  }
}

// ---------------------------------------------------------------------------
// bf16 MFMA GEMM: C[M,N] = A[M,K] @ BT[N,K]^T.  128x128 tile, BK=64, 4 waves,
// single-buffer 32KB staging, XOR-swizzled, swapped-operand mfma (lane holds
// 4 contiguous cols -> direct 8B C stores). 1-D grid, bijective XCD swizzle,
// N-strip fastest. EPI: bias+relu+mask1-bit dropout.
// ---------------------------------------------------------------------------
template <bool EPI, int NSTRIP>
__global__ __launch_bounds__(256) void gemm_bf16(const ushort* __restrict__ A,
                                                 const ushort* __restrict__ BT,
                                                 ushort* __restrict__ C,
                                                 int M, int K, int N,
                                                 const float* __restrict__ bias,
                                                 const unsigned char* __restrict__ mask1) {
  __shared__ __align__(16) ushort lds[16384];  // A 16KB | B 16KB
  const int nwg = gridDim.x;
  const int orig = blockIdx.x;
  const int q = nwg >> 3, r = nwg & 7;
  const int xcd = orig & 7, loc = orig >> 3;
  const int wg = (xcd < r) ? (xcd * (q + 1) + loc)
                           : (r * (q + 1) + (xcd - r) * q + loc);
  const int bm = (wg / NSTRIP) * 128;
  const int bn = (wg % NSTRIP) * 128;

  const int tid = threadIdx.x;
  const int lane = tid & 63;
  const int wv = tid >> 6;
  const int wr = wv >> 1, wc = wv & 1;

  f32x4 acc[4][4] = {};
  const int xorv = (lane & 7) << 4;

  const int nt = K >> 6;
  for (int t = 0; t < nt; ++t) {
    const int k0 = t << 6;
#pragma unroll
    for (int l = 0; l < 4; ++l) {
      int cid = l * 256 + tid;
      int row = cid >> 3;
      int kcol = ((cid & 7) ^ (row & 7)) * 8;
      gload16(A + (size_t)(bm + row) * K + k0 + kcol, (void*)(lds + cid * 8));
      gload16(BT + (size_t)(bn + row) * K + k0 + kcol, (void*)(lds + 8192 + cid * 8));
    }
    __syncthreads();
    const char* Ab = (const char*)lds;
    const char* Bb = (const char*)(lds + 8192);
#pragma unroll
    for (int ks = 0; ks < 2; ++ks) {
      bf16x8 af[4], bf[4];
      const int kb = (ks * 64 + (lane >> 4) * 16) ^ xorv;
#pragma unroll
      for (int i = 0; i < 4; ++i) {
        int arow = wr * 64 + i * 16 + (lane & 15);
        af[i] = *(const bf16x8*)(Ab + arow * 128 + kb);
        int brow = wc * 64 + i * 16 + (lane & 15);
        bf[i] = *(const bf16x8*)(Bb + brow * 128 + kb);
      }
      // swapped operands: D rows <- bf (n), D cols <- af (m)
#pragma unroll
      for (int m = 0; m < 4; ++m)
#pragma unroll
        for (int n = 0; n < 4; ++n)
          acc[m][n] = __builtin_amdgcn_mfma_f32_16x16x32_bf16(bf[n], af[m], acc[m][n], 0, 0, 0);
    }
    __syncthreads();
  }

  // epilogue: lane owns C[grow][gcol..gcol+3] per (m,n) -> direct 8B store
  const int growb = bm + wr * 64 + (lane & 15);
  const int gcolb = bn + wc * 64 + ((lane >> 4) << 2);
  float4 bias_v[4];
  if (EPI) {
#pragma unroll
    for (int n = 0; n < 4; ++n) bias_v[n] = *(const float4*)(bias + gcolb + n * 16);
  }
#pragma unroll
  for (int m = 0; m < 4; ++m) {
    int grow = growb + m * 16;
    unsigned long long mrow = 0;
    if (EPI)
      mrow = *(const unsigned long long*)(mask1 + (((size_t)grow * N + bn + wc * 64) >> 3));
#pragma unroll
    for (int n = 0; n < 4; ++n) {
      int gcol = gcolb + n * 16;
      float v[4];
#pragma unroll
      for (int r2 = 0; r2 < 4; ++r2) {
        float x = acc[m][n][r2];
        if (EPI) {
          x = fmaxf(x + ((const float*)&bias_v[n])[r2], 0.f);
          int bit = (gcol - (bn + wc * 64)) + r2;
          x = ((mrow >> bit) & 1ull) ? 0.f : x * 2.0f;
        }
        v[r2] = x;
      }
      uint2 o;
      o.x = (unsigned)f2b(v[0]) | ((unsigned)f2b(v[1]) << 16);
      o.y = (unsigned)f2b(v[2]) | ((unsigned)f2b(v[3]) << 16);
      *(uint2*)(C + (size_t)grow * N + gcol) = o;
    }
  }
}

// ---------------------------------------------------------------------------
extern "C" void kernel_launch(void* const* d_in, const int* in_sizes, int n_in,
                              void* d_out, int out_size, void* d_ws, size_t ws_size,
                              hipStream_t stream) {
  const float* x  = (const float*)d_in[0];
  const int*   ei = (const int*)d_in[1];
  const float* W1 = (const float*)d_in[2];
  const float* b1 = (const float*)d_in[3];
  const float* W2 = (const float*)d_in[4];
  const float* b2 = (const float*)d_in[5];
  float* out = (float*)d_out;
  (void)in_sizes; (void)n_in; (void)out_size; (void)ws_size;

  const int* row = ei;
  const int* col = ei + N_EDGES;

  // workspace layout (bytes)
  char* ws = (char*)d_ws;
  float*  dinv      = (float*) (ws);                           // 200 KB
  int*    cnt       = (int*)   (ws + (1u << 18));              // 200 KB
  int*    cursor    = (int*)   (ws + (2u << 18));              // 200 KB (adjacent)
  int*    indptr    = (int*)   (ws + (3u << 18));              // 200 KB + 4
  int*    chunkSums = (int*)   (ws + (1u << 20));              // tiny
  int2*   srcW      = (int2*)  (ws + 2u * (1u << 20));         // 6.4 MB
  ushort* W1T       = (ushort*)(ws + 9u * (1u << 20));         // 256 KB [512][256]
  ushort* W2T       = (ushort*)(ws + 9u * (1u << 20) + (1u << 19)); // 256 KB
  unsigned char* mask1 = (unsigned char*)(ws + 10u * (1u << 20)); // 3.21 MB
  unsigned char* mask2 = (unsigned char*)(ws + 14u * (1u << 20)); // 1.61 MB
  ushort* x16       = (ushort*)(ws + 18u * (1u << 20));        // 25.6 MB [50000][256]
  ushort* aggB      = (ushort*)(ws + 44u * (1u << 20));        // 25.6 MB [M_PAD][256]
  ushort* h         = (ushort*)(ws + 70u * (1u << 20));        // 51.2 MB [M_PAD][512]
  ushort* hw2       = (ushort*)(ws + 122u* (1u << 20));        // 25.6 MB [M_PAD][256]

  constexpr U2 K1 = threefry2x32(0u, 42u, 0u, 0u);
  constexpr U2 K2 = threefry2x32(0u, 42u, 0u, 1u);

  // ---- CSR build ----
  (void)hipMemsetAsync(cnt, 0, 2u * (1u << 18), stream);  // cnt + cursor
  deg_kernel<<<(N_EDGES + 255) / 256, 256, 0, stream>>>(col, cnt, N_EDGES);
  const int nChunks = (N_NODES + 1023) / 1024;
  scan_local<<<nChunks, 1024, 0, stream>>>(cnt, indptr, chunkSums, dinv, N_NODES);
  scan_add<<<(N_NODES + 255) / 256, 256, 0, stream>>>(indptr, chunkSums, N_NODES, nChunks, N_EDGES);
  build_csr<<<(N_EDGES + 255) / 256, 256, 0, stream>>>(row, col, indptr, cursor, dinv, srcW, N_EDGES);

  // ---- prep: cvt + mask2 + W transposes + aggB pad zero ----
  prep<<<(N_NODES * IN_C / 4 + 255) / 256, 256, 0, stream>>>(
      x, x16, N_NODES * IN_C / 4, mask2, K2.a, K2.b, N_NODES * 32,
      W1, W2, W1T, W2T, aggB + (size_t)N_NODES * IN_C);

  // ---- layer 1 ----
  gather_lds<false><<<(N_NODES + 3) / 4, 256, 0, stream>>>(
      x16, indptr, srcW, dinv, nullptr, aggB, mask1, nullptr, K1.a, K1.b, N_NODES);
  gemm_bf16<true, HID_C / 128><<<(M_PAD / 128) * (HID_C / 128), 256, 0, stream>>>(
      aggB, W1T, h, M_PAD, IN_C, HID_C, b1, mask1);

  // ---- layer 2 ----
  gemm_bf16<false, OUT_C / 128><<<(M_PAD / 128) * (OUT_C / 128), 256, 0, stream>>>(
      h, W2T, hw2, M_PAD, HID_C, OUT_C, nullptr, nullptr);
  gather_lds<true><<<(N_NODES + 3) / 4, 256, 0, stream>>>(
      hw2, indptr, srcW, dinv, b2, out, nullptr, mask2, 0u, 0u, N_NODES);
}

// Round 17
// 322.794 us; speedup vs baseline: 1.8682x; 1.2251x over previous
//
#include <hip/hip_runtime.h>
#include <stdint.h>

// ---------------------------------------------------------------------------
// GCN: agg1 = A_hat x (8-deep gather + mask1 bitmap)
//      h    = relu+drop(agg1 W1 + b1)   (MFMA GEMM, mask1 bit-test)
//      hw2  = h W2                      (MFMA GEMM, plain)
//      out  = relu+drop(A_hat hw2 + b2) (8-deep gather + mask2 bit-test)
// Gather: r13 structure (best measured) + packed v_pk_fma_f32 accumulate.
// mask2 generated in prep. CSR = {src_byte_off, dinv[src]}.
// ---------------------------------------------------------------------------

#define N_NODES 50000
#define N_EDGES 800000
#define M_PAD   50048   // 391 * 128
#define IN_C 256
#define HID_C 512
#define OUT_C 256

typedef __attribute__((ext_vector_type(8))) short bf16x8;
typedef __attribute__((ext_vector_type(4))) float f32x4;
typedef __attribute__((ext_vector_type(2))) float f32x2;

struct U2 { unsigned a, b; };

__host__ __device__ constexpr unsigned rotl32(unsigned x, int d) {
  return (x << d) | (x >> (32 - d));
}

#define TF_ROUND(r) { x0 += x1; x1 = rotl32(x1, (r)); x1 ^= x0; }

__host__ __device__ constexpr U2 threefry2x32(unsigned k0, unsigned k1,
                                              unsigned x0, unsigned x1) {
  unsigned ks2 = k0 ^ k1 ^ 0x1BD11BDAu;
  x0 += k0; x1 += k1;
  TF_ROUND(13) TF_ROUND(15) TF_ROUND(26) TF_ROUND(6)  x0 += k1;  x1 += ks2 + 1u;
  TF_ROUND(17) TF_ROUND(29) TF_ROUND(16) TF_ROUND(24) x0 += ks2; x1 += k0 + 2u;
  TF_ROUND(13) TF_ROUND(15) TF_ROUND(26) TF_ROUND(6)  x0 += k0;  x1 += k1 + 3u;
  TF_ROUND(17) TF_ROUND(29) TF_ROUND(16) TF_ROUND(24) x0 += k1;  x1 += ks2 + 4u;
  TF_ROUND(13) TF_ROUND(15) TF_ROUND(26) TF_ROUND(6)  x0 += ks2; x1 += k0 + 5u;
  return U2{x0, x1};
}

__device__ __forceinline__ ushort f2b(float f) {  // RTNE
  unsigned u = __builtin_bit_cast(unsigned, f);
  unsigned r = (u + 0x7fffu + ((u >> 16) & 1u)) >> 16;
  return (ushort)r;
}
__device__ __forceinline__ float b2f_hi(unsigned u) {
  return __builtin_bit_cast(float, u & 0xffff0000u);
}
__device__ __forceinline__ float b2f_lo(unsigned u) {
  return __builtin_bit_cast(float, u << 16);
}

__device__ __forceinline__ void gload16(const void* g, void* l) {
  __builtin_amdgcn_global_load_lds(
      (const __attribute__((address_space(1))) void*)g,
      (__attribute__((address_space(3))) void*)l, 16, 0, 0);
}

// packed accumulate: 2x v_pk_fma_f32 per edge-uint2
#define ROW_ACC(u, w)                                                          \
  { f32x2 _x = { b2f_lo((u).x), b2f_hi((u).x) };                               \
    f32x2 _y = { b2f_lo((u).y), b2f_hi((u).y) };                               \
    p01 += _x * (w); p23 += _y * (w); }

// ---------------------------------------------------------------------------
// degree / scan(+dinv) / merged chunk-scan+add / CSR build
// ---------------------------------------------------------------------------
__global__ void deg_kernel(const int* __restrict__ col, int* __restrict__ cnt, int E) {
  int e = blockIdx.x * 256 + threadIdx.x;
  if (e < E) atomicAdd(&cnt[col[e]], 1);
}

__global__ __launch_bounds__(1024) void scan_local(const int* __restrict__ cnt,
                                                   int* __restrict__ indptr,
                                                   int* __restrict__ chunkSums,
                                                   float* __restrict__ dinv, int n) {
  __shared__ int s[1024];
  int gid = blockIdx.x * 1024 + threadIdx.x;
  int v = (gid < n) ? cnt[gid] : 0;
  if (gid < n) dinv[gid] = rsqrtf((float)v + 1.0f);
  s[threadIdx.x] = v;
  __syncthreads();
#pragma unroll
  for (int off = 1; off < 1024; off <<= 1) {
    int t = (threadIdx.x >= off) ? s[threadIdx.x - off] : 0;
    __syncthreads();
    s[threadIdx.x] += t;
    __syncthreads();
  }
  if (gid < n) indptr[gid] = s[threadIdx.x] - v;
  if (threadIdx.x == 1023) chunkSums[blockIdx.x] = s[1023];
}

__global__ void scan_add(int* __restrict__ indptr, const int* __restrict__ chunkSums,
                         int n, int nChunks, int total) {
  __shared__ int sc[64];
  int gid = blockIdx.x * 256 + threadIdx.x;
  if (threadIdx.x < 64) {
    int lane = threadIdx.x;
    int v = (lane < nChunks) ? chunkSums[lane] : 0;
    int incl = v;
#pragma unroll
    for (int off = 1; off < 64; off <<= 1) {
      int t = __shfl_up(incl, off);
      if (lane >= off) incl += t;
    }
    sc[lane] = incl - v;  // exclusive prefix
  }
  __syncthreads();
  if (gid < n) indptr[gid] += sc[gid >> 10];
  if (gid == 0) indptr[n] = total;
}

__global__ void build_csr(const int* __restrict__ row, const int* __restrict__ col,
                          const int* __restrict__ indptr, int* __restrict__ cursor,
                          const float* __restrict__ dinv,
                          int2* __restrict__ srcW, int E) {
  int e = blockIdx.x * 256 + threadIdx.x;
  if (e < E) {
    int r = row[e];
    int c = col[e];
    int p = indptr[c] + atomicAdd(&cursor[c], 1);
    srcW[p] = make_int2(r << 9, __builtin_bit_cast(int, dinv[r]));  // byte offset
  }
}

// ---------------------------------------------------------------------------
// prep: x->bf16 cvt, mask2 bitmap gen, W1T/W2T transpose-cvt, aggB pad zero.
// ---------------------------------------------------------------------------
__global__ void prep(const float* __restrict__ x, ushort* __restrict__ x16, int n4,
                     unsigned char* __restrict__ mask2,
                     unsigned k20, unsigned k21, int nMaskBytes,
                     const float* __restrict__ W1, const float* __restrict__ W2,
                     ushort* __restrict__ W1T, ushort* __restrict__ W2T,
                     ushort* __restrict__ padDst) {
  int i = blockIdx.x * 256 + threadIdx.x;
  if (i < n4) {
    float4 v = *(const float4*)(x + (size_t)i * 4);
    ushort4 o = make_ushort4(f2b(v.x), f2b(v.y), f2b(v.z), f2b(v.w));
    *(ushort4*)(x16 + (size_t)i * 4) = o;
  }
  if (i < nMaskBytes) {
    unsigned eb = (unsigned)i * 8u;
    unsigned byte = 0;
#pragma unroll
    for (int j = 0; j < 8; ++j) {
      U2 r = threefry2x32(k20, k21, 0u, eb + (unsigned)j);
      byte |= (((r.a ^ r.b) >> 31) & 1u) << j;
    }
    mask2[i] = (unsigned char)byte;
  }
  if (i < IN_C * HID_C) {        // W1T[n][k] = bf16(W1[k][n])
    int k = i & (IN_C - 1);
    int n = i >> 8;
    W1T[i] = f2b(W1[(size_t)k * HID_C + n]);
  } else if (i < IN_C * HID_C + HID_C * OUT_C) {
    int j = i - IN_C * HID_C;    // W2T[n][k] = bf16(W2[k][n])
    int k = j & (HID_C - 1);
    int n = j >> 9;
    W2T[j] = f2b(W2[(size_t)k * OUT_C + n]);
  }
  if (i < (M_PAD - N_NODES) * IN_C / 8) {  // zero pad rows of aggB
    uint4 z = {0u, 0u, 0u, 0u};
    *(uint4*)(padDst + (size_t)i * 8) = z;
  }
}

// ---------------------------------------------------------------------------
// gather over CSR pairs (r13 structure): one wave per node, 64 lanes x 8B,
// 8-deep unrolled, packed pk_fma accumulate.
// EPI=false: bf16 out + mask1 bitmap. EPI=true: bias+relu+mask2 drop, fp32.
// ---------------------------------------------------------------------------
template <bool EPI>
__global__ __launch_bounds__(256) void gather8(const ushort* __restrict__ X,
                                               const int* __restrict__ indptr,
                                               const int2* __restrict__ srcW,
                                               const float* __restrict__ dinv,
                                               const float* __restrict__ bias,
                                               void* __restrict__ outp,
                                               unsigned char* __restrict__ mask1Gen,
                                               const unsigned char* __restrict__ maskUse,
                                               unsigned k10, unsigned k11, int N) {
  int wid = (blockIdx.x * 256 + threadIdx.x) >> 6;
  int lane = threadIdx.x & 63;
  if (wid >= N) return;
  int beg = __builtin_amdgcn_readfirstlane(indptr[wid]);
  int end = __builtin_amdgcn_readfirstlane(indptr[wid + 1]);
  float dc = dinv[wid];
  const int f0 = lane * 4;
  const char* Xb = (const char*)X + (unsigned)(lane * 8);  // per-lane base
  f32x2 p01 = {0.f, 0.f}, p23 = {0.f, 0.f};
  {
    uint2 sv = *(const uint2*)(Xb + ((size_t)wid << 9));
    ROW_ACC(sv, dc);
  }

  int e = beg;
  for (; e + 8 <= end; e += 8) {
    int2 q0 = srcW[e + 0], q1 = srcW[e + 1], q2 = srcW[e + 2], q3 = srcW[e + 3];
    int2 q4 = srcW[e + 4], q5 = srcW[e + 5], q6 = srcW[e + 6], q7 = srcW[e + 7];
    uint2 v0 = *(const uint2*)(Xb + (unsigned)q0.x);
    uint2 v1 = *(const uint2*)(Xb + (unsigned)q1.x);
    uint2 v2 = *(const uint2*)(Xb + (unsigned)q2.x);
    uint2 v3 = *(const uint2*)(Xb + (unsigned)q3.x);
    uint2 v4 = *(const uint2*)(Xb + (unsigned)q4.x);
    uint2 v5 = *(const uint2*)(Xb + (unsigned)q5.x);
    uint2 v6 = *(const uint2*)(Xb + (unsigned)q6.x);
    uint2 v7 = *(const uint2*)(Xb + (unsigned)q7.x);
    ROW_ACC(v0, __builtin_bit_cast(float, q0.y));
    ROW_ACC(v1, __builtin_bit_cast(float, q1.y));
    ROW_ACC(v2, __builtin_bit_cast(float, q2.y));
    ROW_ACC(v3, __builtin_bit_cast(float, q3.y));
    ROW_ACC(v4, __builtin_bit_cast(float, q4.y));
    ROW_ACC(v5, __builtin_bit_cast(float, q5.y));
    ROW_ACC(v6, __builtin_bit_cast(float, q6.y));
    ROW_ACC(v7, __builtin_bit_cast(float, q7.y));
  }
  for (; e + 2 <= end; e += 2) {
    int2 q0 = srcW[e + 0], q1 = srcW[e + 1];
    uint2 v0 = *(const uint2*)(Xb + (unsigned)q0.x);
    uint2 v1 = *(const uint2*)(Xb + (unsigned)q1.x);
    ROW_ACC(v0, __builtin_bit_cast(float, q0.y));
    ROW_ACC(v1, __builtin_bit_cast(float, q1.y));
  }
  if (e < end) {
    int2 q0 = srcW[e];
    uint2 v0 = *(const uint2*)(Xb + (unsigned)q0.x);
    ROW_ACC(v0, __builtin_bit_cast(float, q0.y));
  }
  float a0 = p01.x * dc, a1 = p01.y * dc, a2 = p23.x * dc, a3 = p23.y * dc;

  if (EPI) {
    float4 bv = *(const float4*)(bias + f0);
    unsigned mk = maskUse[(size_t)wid * 32 + (lane >> 1)];
    int sh = (lane & 1) * 4;
    float v0 = fmaxf(a0 + bv.x, 0.f);
    float v1 = fmaxf(a1 + bv.y, 0.f);
    float v2 = fmaxf(a2 + bv.z, 0.f);
    float v3 = fmaxf(a3 + bv.w, 0.f);
    v0 = ((mk >> (sh + 0)) & 1u) ? 0.f : v0 * 2.0f;
    v1 = ((mk >> (sh + 1)) & 1u) ? 0.f : v1 * 2.0f;
    v2 = ((mk >> (sh + 2)) & 1u) ? 0.f : v2 * 2.0f;
    v3 = ((mk >> (sh + 3)) & 1u) ? 0.f : v3 * 2.0f;
    *(float4*)((float*)outp + (size_t)wid * 256 + f0) = make_float4(v0, v1, v2, v3);
  } else {
    uint2 o;
    o.x = (unsigned)f2b(a0) | ((unsigned)f2b(a1) << 16);
    o.y = (unsigned)f2b(a2) | ((unsigned)f2b(a3) << 16);
    *(uint2*)((ushort*)outp + (size_t)wid * 256 + f0) = o;
    // layer-1 mask: lane packs bits for h elements [gl*8, gl*8+8)
    unsigned gl = (unsigned)wid * 64u + (unsigned)lane;
    unsigned eb = gl * 8u;
    unsigned byte = 0;
#pragma unroll
    for (int j = 0; j < 8; ++j) {
      U2 r = threefry2x32(k10, k11, 0u, eb + (unsigned)j);
      byte |= (((r.a ^ r.b) >> 31) & 1u) << j;
    }
    mask1Gen[gl] = (unsigned char)byte;
  }
}

// ---------------------------------------------------------------------------
// bf16 MFMA GEMM: C[M,N] = A[M,K] @ BT[N,K]^T.  128x128 tile, BK=64, 4 waves,
// single-buffer 32KB staging, XOR-swizzled, swapped-operand mfma (lane holds
// 4 contiguous cols -> direct 8B C stores). 1-D grid, bijective XCD swizzle,
// N-strip fastest. EPI: bias+relu+mask1-bit dropout.
// ---------------------------------------------------------------------------
template <bool EPI, int NSTRIP>
__global__ __launch_bounds__(256) void gemm_bf16(const ushort* __restrict__ A,
                                                 const ushort* __restrict__ BT,
                                                 ushort* __restrict__ C,
                                                 int M, int K, int N,
                                                 const float* __restrict__ bias,
                                                 const unsigned char* __restrict__ mask1) {
  __shared__ __align__(16) ushort lds[16384];  // A 16KB | B 16KB
  const int nwg = gridDim.x;
  const int orig = blockIdx.x;
  const int q = nwg >> 3, r = nwg & 7;
  const int xcd = orig & 7, loc = orig >> 3;
  const int wg = (xcd < r) ? (xcd * (q + 1) + loc)
                           : (r * (q + 1) + (xcd - r) * q + loc);
  const int bm = (wg / NSTRIP) * 128;
  const int bn = (wg % NSTRIP) * 128;

  const int tid = threadIdx.x;
  const int lane = tid & 63;
  const int wv = tid >> 6;
  const int wr = wv >> 1, wc = wv & 1;

  f32x4 acc[4][4] = {};
  const int xorv = (lane & 7) << 4;

  const int nt = K >> 6;
  for (int t = 0; t < nt; ++t) {
    const int k0 = t << 6;
#pragma unroll
    for (int l = 0; l < 4; ++l) {
      int cid = l * 256 + tid;
      int row = cid >> 3;
      int kcol = ((cid & 7) ^ (row & 7)) * 8;
      gload16(A + (size_t)(bm + row) * K + k0 + kcol, (void*)(lds + cid * 8));
      gload16(BT + (size_t)(bn + row) * K + k0 + kcol, (void*)(lds + 8192 + cid * 8));
    }
    __syncthreads();
    const char* Ab = (const char*)lds;
    const char* Bb = (const char*)(lds + 8192);
#pragma unroll
    for (int ks = 0; ks < 2; ++ks) {
      bf16x8 af[4], bf[4];
      const int kb = (ks * 64 + (lane >> 4) * 16) ^ xorv;
#pragma unroll
      for (int i = 0; i < 4; ++i) {
        int arow = wr * 64 + i * 16 + (lane & 15);
        af[i] = *(const bf16x8*)(Ab + arow * 128 + kb);
        int brow = wc * 64 + i * 16 + (lane & 15);
        bf[i] = *(const bf16x8*)(Bb + brow * 128 + kb);
      }
      // swapped operands: D rows <- bf (n), D cols <- af (m)
#pragma unroll
      for (int m = 0; m < 4; ++m)
#pragma unroll
        for (int n = 0; n < 4; ++n)
          acc[m][n] = __builtin_amdgcn_mfma_f32_16x16x32_bf16(bf[n], af[m], acc[m][n], 0, 0, 0);
    }
    __syncthreads();
  }

  // epilogue: lane owns C[grow][gcol..gcol+3] per (m,n) -> direct 8B store
  const int growb = bm + wr * 64 + (lane & 15);
  const int gcolb = bn + wc * 64 + ((lane >> 4) << 2);
  float4 bias_v[4];
  if (EPI) {
#pragma unroll
    for (int n = 0; n < 4; ++n) bias_v[n] = *(const float4*)(bias + gcolb + n * 16);
  }
#pragma unroll
  for (int m = 0; m < 4; ++m) {
    int grow = growb + m * 16;
    unsigned long long mrow = 0;
    if (EPI)
      mrow = *(const unsigned long long*)(mask1 + (((size_t)grow * N + bn + wc * 64) >> 3));
#pragma unroll
    for (int n = 0; n < 4; ++n) {
      int gcol = gcolb + n * 16;
      float v[4];
#pragma unroll
      for (int r2 = 0; r2 < 4; ++r2) {
        float x = acc[m][n][r2];
        if (EPI) {
          x = fmaxf(x + ((const float*)&bias_v[n])[r2], 0.f);
          int bit = (gcol - (bn + wc * 64)) + r2;
          x = ((mrow >> bit) & 1ull) ? 0.f : x * 2.0f;
        }
        v[r2] = x;
      }
      uint2 o;
      o.x = (unsigned)f2b(v[0]) | ((unsigned)f2b(v[1]) << 16);
      o.y = (unsigned)f2b(v[2]) | ((unsigned)f2b(v[3]) << 16);
      *(uint2*)(C + (size_t)grow * N + gcol) = o;
    }
  }
}

// ---------------------------------------------------------------------------
extern "C" void kernel_launch(void* const* d_in, const int* in_sizes, int n_in,
                              void* d_out, int out_size, void* d_ws, size_t ws_size,
                              hipStream_t stream) {
  const float* x  = (const float*)d_in[0];
  const int*   ei = (const int*)d_in[1];
  const float* W1 = (const float*)d_in[2];
  const float* b1 = (const float*)d_in[3];
  const float* W2 = (const float*)d_in[4];
  const float* b2 = (const float*)d_in[5];
  float* out = (float*)d_out;
  (void)in_sizes; (void)n_in; (void)out_size; (void)ws_size;

  const int* row = ei;
  const int* col = ei + N_EDGES;

  // workspace layout (bytes)
  char* ws = (char*)d_ws;
  float*  dinv      = (float*) (ws);                           // 200 KB
  int*    cnt       = (int*)   (ws + (1u << 18));              // 200 KB
  int*    cursor    = (int*)   (ws + (2u << 18));              // 200 KB (adjacent)
  int*    indptr    = (int*)   (ws + (3u << 18));              // 200 KB + 4
  int*    chunkSums = (int*)   (ws + (1u << 20));              // tiny
  int2*   srcW      = (int2*)  (ws + 2u * (1u << 20));         // 6.4 MB
  ushort* W1T       = (ushort*)(ws + 9u * (1u << 20));         // 256 KB [512][256]
  ushort* W2T       = (ushort*)(ws + 9u * (1u << 20) + (1u << 19)); // 256 KB
  unsigned char* mask1 = (unsigned char*)(ws + 10u * (1u << 20)); // 3.21 MB
  unsigned char* mask2 = (unsigned char*)(ws + 14u * (1u << 20)); // 1.61 MB
  ushort* x16       = (ushort*)(ws + 18u * (1u << 20));        // 25.6 MB [50000][256]
  ushort* aggB      = (ushort*)(ws + 44u * (1u << 20));        // 25.6 MB [M_PAD][256]
  ushort* h         = (ushort*)(ws + 70u * (1u << 20));        // 51.2 MB [M_PAD][512]
  ushort* hw2       = (ushort*)(ws + 122u* (1u << 20));        // 25.6 MB [M_PAD][256]

  constexpr U2 K1 = threefry2x32(0u, 42u, 0u, 0u);
  constexpr U2 K2 = threefry2x32(0u, 42u, 0u, 1u);

  // ---- CSR build ----
  (void)hipMemsetAsync(cnt, 0, 2u * (1u << 18), stream);  // cnt + cursor
  deg_kernel<<<(N_EDGES + 255) / 256, 256, 0, stream>>>(col, cnt, N_EDGES);
  const int nChunks = (N_NODES + 1023) / 1024;
  scan_local<<<nChunks, 1024, 0, stream>>>(cnt, indptr, chunkSums, dinv, N_NODES);
  scan_add<<<(N_NODES + 255) / 256, 256, 0, stream>>>(indptr, chunkSums, N_NODES, nChunks, N_EDGES);
  build_csr<<<(N_EDGES + 255) / 256, 256, 0, stream>>>(row, col, indptr, cursor, dinv, srcW, N_EDGES);

  // ---- prep: cvt + mask2 + W transposes + aggB pad zero ----
  prep<<<(N_NODES * IN_C / 4 + 255) / 256, 256, 0, stream>>>(
      x, x16, N_NODES * IN_C / 4, mask2, K2.a, K2.b, N_NODES * 32,
      W1, W2, W1T, W2T, aggB + (size_t)N_NODES * IN_C);

  // ---- layer 1 ----
  gather8<false><<<(N_NODES + 3) / 4, 256, 0, stream>>>(
      x16, indptr, srcW, dinv, nullptr, aggB, mask1, nullptr, K1.a, K1.b, N_NODES);
  gemm_bf16<true, HID_C / 128><<<(M_PAD / 128) * (HID_C / 128), 256, 0, stream>>>(
      aggB, W1T, h, M_PAD, IN_C, HID_C, b1, mask1);

  // ---- layer 2 ----
  gemm_bf16<false, OUT_C / 128><<<(M_PAD / 128) * (OUT_C / 128), 256, 0, stream>>>(
      h, W2T, hw2, M_PAD, HID_C, OUT_C, nullptr, nullptr);
  gather8<true><<<(N_NODES + 3) / 4, 256, 0, stream>>>(
      hw2, indptr, srcW, dinv, b2, out, nullptr, mask2, 0u, 0u, N_NODES);
}